// Round 20
// baseline (13.826 us; speedup 1.0000x reference)
//
#include <hip/hip_runtime.h>
#include <hip/hip_fp16.h>
#include <math.h>

#define N_G   4096
#define IMW   96
#define TILE  6             // 6x6 px tiles
#define TILES_X 16
#define NTILE (TILES_X*TILES_X)   // 256 blocks == 256 CUs
#define NTHR  1024          // 16 waves per block
#define NW    (NTHR/64)
#define NPX   (TILE*TILE)   // 36 pixels per tile
#define NSEG  16            // depth segments per pixel == NW
#define BCAP  1536          // max bound-phase survivors per tile
#define CAP   512           // max exact survivors per tile
#define FXI   (1.0f/96.0f)
#define NEARP 0.3f
#define EPSV  1e-8f
#define LOG2E 1.4426950408889634f
#define LN2   0.6931471805599453f
#define CULL_K 16.0f        // drop alpha < opa * 2^-16 within tile

typedef unsigned long long ull;
typedef __attribute__((ext_vector_type(2))) unsigned long long ull2;

// Single kernel, one block per 6x6 tile (256 blocks = 1/CU, 16 waves each).
// Stage pos/scale/opa coalesced f4 -> LDS once; Phase A processes 4
// consecutive gaussians/thread from 7 ds_read_b128 (single stage, per-axis
// Frobenius bound). Phase B reads stash (scattered b32) + quat/rgb global,
// exact ellipse-AABB cull, packed f16-color payload. C: rank sort permutes
// payload. D: wave-aligned composite, 2 broadcast b128/elem. E: merge+store.
// pk0s/pk1s/psum/pix alias the stash after B (barrier-separated).
__global__ __launch_bounds__(NTHR, 1) void splat_k(
    const float* __restrict__ pos, const float* __restrict__ rgb,
    const float* __restrict__ opa, const float* __restrict__ quat,
    const float* __restrict__ scale, const float* __restrict__ rot,
    const float* __restrict__ tran, float* __restrict__ out)
{
    __shared__ __align__(16) float stash[N_G*7];   // 112 KB: pos|scale|opa
    __shared__ unsigned int bl[BCAP];
    __shared__ __align__(16) ull skey[CAP+2];
    __shared__ float4 pk0[CAP], pk1[CAP];          // unsorted packed params
    __shared__ int bcnt_sh, cnt_sh;

    float* spos   = stash;            // [N_G*3]
    float* sscale = stash + N_G*3;    // [N_G*3]
    float* sopa   = stash + N_G*6;    // [N_G]
    // aliases into stash, valid after the post-B barrier:
    float4* pk0s = (float4*)stash;                    // floats [0,2048)
    float4* pk1s = pk0s + CAP;                        // floats [2048,4096)
    int (*psum)[CAP] = (int (*)[CAP])(stash + 4096);  // floats [4096,6144)
    float4* pix = (float4*)(stash + 6144);            // floats [6144,8448)

    const int t = threadIdx.x;
    const int tile = blockIdx.x;
    const int tx = tile % TILES_X, ty = tile / TILES_X;
    const float u0 = ((float)(tx*TILE) + 0.5f - 48.0f) * FXI;
    const float u1 = u0 + (TILE-1) * FXI;
    const float v0 = ((float)(ty*TILE) + 0.5f - 48.0f) * FXI;
    const float v1 = v0 + (TILE-1) * FXI;
    const int wid = t >> 6, lane = t & 63;

    float R00=rot[0],R01=rot[1],R02=rot[2];
    float R10=rot[3],R11=rot[4],R12=rot[5];
    float R20=rot[6],R21=rot[7],R22=rot[8];
    float t0=tran[0], t1=tran[1], t2=tran[2];

    // ---- coalesced f4 staging of pos/scale/opa into LDS ----
    {
        const float4* p4 = (const float4*)pos;
        const float4* s4 = (const float4*)scale;
        const float4* o4 = (const float4*)opa;
        float4* sp4 = (float4*)spos;
        float4* ss4 = (float4*)sscale;
        float4* so4 = (float4*)sopa;
        #pragma unroll
        for (int k = 0; k < 3; k++) {
            sp4[k*NTHR + t] = p4[k*NTHR + t];
            ss4[k*NTHR + t] = s4[k*NTHR + t];
        }
        so4[t] = o4[t];
    }
    if (t == 0) { bcnt_sh = 0; cnt_sh = 0; }
    __syncthreads();

    // ---- Phase A: per-axis Frobenius bound cull, 4 gaussians/thread ----
    {
        const float4* sp4 = (const float4*)spos;
        const float4* ss4 = (const float4*)sscale;
        const float4* so4 = (const float4*)sopa;
        float4 P0 = sp4[3*t], P1 = sp4[3*t+1], P2 = sp4[3*t+2];
        float4 S0 = ss4[3*t], S1 = ss4[3*t+1], S2 = ss4[3*t+2];
        float4 OO = so4[t];
        const float gx[4] = {P0.x, P0.w, P1.z, P2.y};
        const float gy[4] = {P0.y, P1.x, P1.w, P2.z};
        const float gz[4] = {P0.z, P1.y, P2.x, P2.w};
        const float sx[4] = {S0.x, S0.w, S1.z, S2.y};
        const float sy[4] = {S0.y, S1.x, S1.w, S2.z};
        const float sz[4] = {S0.z, S1.y, S2.x, S2.w};
        const float op[4] = {OO.x, OO.y, OO.z, OO.w};

        bool fl[4];
        #pragma unroll
        for (int j = 0; j < 4; j++) {
            float x = R00*gx[j] + R01*gy[j] + R02*gz[j] + t0;
            float y = R10*gx[j] + R11*gy[j] + R12*gz[j] + t1;
            float z = R20*gx[j] + R21*gy[j] + R22*gz[j] + t2;
            float invz = 1.0f/z;
            float mu = x*invz, mv = y*invz;

            // per-axis row norms of J (== of J*W, W orthonormal)
            float inz2 = invz*invz;
            float fnu = inz2 + x*x*inz2*inz2;
            float fnv = inz2 + y*y*inz2*inz2;
            float smax = fmaxf(fmaxf(fabsf(sx[j]), fabsf(sy[j])), fabsf(sz[j])) + 1e-4f;
            float s2 = smax*smax;
            float amp = CULL_K + 1.0f + fminf(0.0f, op[j]*LOG2E);
            float sc2 = amp * (2.0f*LN2) * 1.02f;
            float eu2b = sc2 * (fnu*s2 + EPSV);
            float ev2b = sc2 * (fnv*s2 + EPSV);

            float cu = fminf(fmaxf(mu, u0), u1);
            float cv = fminf(fmaxf(mv, v0), v1);
            float ddx = mu - cu, ddy = mv - cv;
            fl[j] = (z > NEARP) && (amp > 0.0f) &&
                    (ddx*ddx <= eu2b) && (ddy*ddy <= ev2b);
        }

        ull b0 = __ballot(fl[0]), b1 = __ballot(fl[1]);
        ull b2 = __ballot(fl[2]), b3 = __ballot(fl[3]);
        int nm = __popcll(b0) + __popcll(b1) + __popcll(b2) + __popcll(b3);
        int base = 0;
        if (lane == 0 && nm) base = atomicAdd(&bcnt_sh, nm);
        base = __shfl(base, 0);
        ull lm = (1ull << lane) - 1ull;
        int o0 = __popcll(b0), o1 = o0 + __popcll(b1), o2 = o1 + __popcll(b2);
        if (fl[0]) { int p = base + __popcll(b0 & lm);
                     if (p < BCAP) bl[p] = (unsigned int)(4*t + 0); }
        if (fl[1]) { int p = base + o0 + __popcll(b1 & lm);
                     if (p < BCAP) bl[p] = (unsigned int)(4*t + 1); }
        if (fl[2]) { int p = base + o1 + __popcll(b2 & lm);
                     if (p < BCAP) bl[p] = (unsigned int)(4*t + 2); }
        if (fl[3]) { int p = base + o2 + __popcll(b3 & lm);
                     if (p < BCAP) bl[p] = (unsigned int)(4*t + 3); }
    }
    __syncthreads();
    int bcnt = bcnt_sh; if (bcnt > BCAP) bcnt = BCAP;

    // ---- Phase B: exact params (stash inputs) + ellipse-AABB cull ----
    for (int s0i = 0; s0i < bcnt; s0i += NTHR) {
        int s = s0i + t;
        bool flag = false;
        float4 o0, o1; float rr = 0.0f;
        unsigned int gi = 0;
        if (s < bcnt) {
            gi = bl[s];
            float p0 = spos[gi*3+0], p1 = spos[gi*3+1], p2 = spos[gi*3+2];
            float x = R00*p0 + R01*p1 + R02*p2 + t0;
            float y = R10*p0 + R11*p1 + R12*p2 + t1;
            float z = R20*p0 + R21*p1 + R22*p2 + t2;
            rr = sqrtf(x*x + y*y + z*z);
            float invz = 1.0f/z;
            float mu = x*invz, mv = y*invz;

            float J02 = -x*invz*invz, J12 = -y*invz*invz;
            float JW00 = invz*R00 + J02*R20;
            float JW01 = invz*R01 + J02*R21;
            float JW02 = invz*R02 + J02*R22;
            float JW10 = invz*R10 + J12*R20;
            float JW11 = invz*R11 + J12*R21;
            float JW12 = invz*R12 + J12*R22;

            const float4 qv = ((const float4*)quat)[gi];
            float qw=qv.x, qx=qv.y, qy=qv.z, qz=qv.w;
            float qn = sqrtf(qw*qw+qx*qx+qy*qy+qz*qz) + 1e-12f;
            float qi = 1.0f/qn;
            qw*=qi; qx*=qi; qy*=qi; qz*=qi;
            float Q00=1.f-2.f*(qy*qy+qz*qz), Q01=2.f*(qx*qy-qw*qz), Q02=2.f*(qx*qz+qw*qy);
            float Q10=2.f*(qx*qy+qw*qz), Q11=1.f-2.f*(qx*qx+qz*qz), Q12=2.f*(qy*qz-qw*qx);
            float Q20=2.f*(qx*qz-qw*qy), Q21=2.f*(qy*qz+qw*qx), Q22=1.f-2.f*(qx*qx+qy*qy);

            float sa=fabsf(sscale[gi*3+0])+1e-4f;
            float sb=fabsf(sscale[gi*3+1])+1e-4f;
            float sc=fabsf(sscale[gi*3+2])+1e-4f;
            float A00=Q00*sa,A01=Q01*sb,A02=Q02*sc;
            float A10=Q10*sa,A11=Q11*sb,A12=Q12*sc;
            float A20=Q20*sa,A21=Q21*sb,A22=Q22*sc;
            float C00=A00*A00+A01*A01+A02*A02;
            float C01=A00*A10+A01*A11+A02*A12;
            float C02=A00*A20+A01*A21+A02*A22;
            float C11=A10*A10+A11*A11+A12*A12;
            float C12=A10*A20+A11*A21+A12*A22;
            float C22=A20*A20+A21*A21+A22*A22;
            float M00=JW00*C00+JW01*C01+JW02*C02;
            float M01=JW00*C01+JW01*C11+JW02*C12;
            float M02=JW00*C02+JW01*C12+JW02*C22;
            float M10=JW10*C00+JW11*C01+JW12*C02;
            float M11=JW10*C01+JW11*C11+JW12*C12;
            float M12=JW10*C02+JW11*C12+JW12*C22;
            float a  = M00*JW00+M01*JW01+M02*JW02 + EPSV;
            float d  = M10*JW10+M11*JW11+M12*JW12 + EPSV;
            float bb = 0.5f*((M00*JW10+M01*JW11+M02*JW12)+(M10*JW00+M11*JW01+M12*JW02));
            float invdet = 1.0f/(a*d - bb*bb);
            float iaP = -0.5f*d*invdet*LOG2E;
            float ibP =  bb*invdet*LOG2E;
            float idP = -0.5f*a*invdet*LOG2E;

            float sig_o = 1.0f/(1.0f+__expf(-sopa[gi]));
            float opa_eff = (z > NEARP) ? sig_o : 0.0f;

            // exact ellipse-AABB cull: extent_u^2 = K*q11/detQ etc.
            float q00 = -iaP, q01 = -0.5f*ibP, q11 = -idP;
            float detQ = q00*q11 - q01*q01;
            float K = CULL_K + log2f(opa_eff);   // -inf when opa_eff==0

            float cu = fminf(fmaxf(mu, u0), u1);
            float cv = fminf(fmaxf(mv, v0), v1);
            float ddx = mu - cu, ddy = mv - cv;
            flag = (ddx*ddx*detQ <= K*q11) && (ddy*ddy*detQ <= K*q00);

            if (flag) {
                float c0 = 1.0f/(1.0f+__expf(-rgb[gi*3+0]));
                float c1 = 1.0f/(1.0f+__expf(-rgb[gi*3+1]));
                float c2 = 1.0f/(1.0f+__expf(-rgb[gi*3+2]));
                unsigned int c01p =
                    (unsigned int)__half_as_ushort(__float2half_rn(c0)) |
                    ((unsigned int)__half_as_ushort(__float2half_rn(c1)) << 16);
                unsigned int c2p =
                    (unsigned int)__half_as_ushort(__float2half_rn(c2));
                o0 = make_float4(mu, mv, iaP, ibP);
                o1 = make_float4(idP, opa_eff,
                                 __uint_as_float(c01p), __uint_as_float(c2p));
            }
        }
        ull m = __ballot(flag);
        int nm = __popcll(m);
        int base = 0;
        if (lane == 0 && nm) base = atomicAdd(&cnt_sh, nm);
        base = __shfl(base, 0);
        if (flag) {
            int p = base + __popcll(m & ((1ull << lane) - 1ull));
            if (p < CAP) {
                pk0[p] = o0; pk1[p] = o1;
                // key = (rr_bits, gi): globally unique -> reference's stable
                // argsort order restricted to survivors
                skey[p] = ((ull)__float_as_uint(rr) << 32) | gi;
            }
        }
    }
    __syncthreads();   // stash dead from here; aliases become valid
    int cnt = cnt_sh; if (cnt > CAP) cnt = CAP;

    // ---- Phase C: rank sort; scatter permutes PARAM PAYLOAD into order ----
    if (t == 0 && (cnt & 1)) skey[cnt] = ~0ull;  // pad sorts last, never scattered
    __syncthreads();
    int cnt2 = cnt + (cnt & 1);
    int nq = cnt2 >> 1;                          // total ull2 words
    const ull2* sk2 = (const ull2*)skey;
    const int g = t >> 8, e = t & 255;
    const bool h1 = (e < cnt), h2 = (e + 256 < cnt);
    if (h1) {
        ull kv1 = skey[e];
        ull kv2 = h2 ? skey[e + 256] : 0;
        int wA = (nq * g) >> 2;
        int wB = (nq * (g+1)) >> 2;
        int c1 = 0, c2 = 0;
        for (int w = wA; w < wB; w++) {
            ull2 p = sk2[w];                     // broadcast: shared by both elems
            c1 += (p.x < kv1) ? 1 : 0;
            c1 += (p.y < kv1) ? 1 : 0;
            c2 += (p.x < kv2) ? 1 : 0;
            c2 += (p.y < kv2) ? 1 : 0;
        }
        psum[g][e] = c1;
        if (h2) psum[g][e + 256] = c2;
    }
    __syncthreads();
    if (t < 256 && h1) {
        int r1 = psum[0][e] + psum[1][e] + psum[2][e] + psum[3][e];
        pk0s[r1] = pk0[e];
        pk1s[r1] = pk1[e];
        if (h2) {
            int e2 = e + 256;
            int r2 = psum[0][e2] + psum[1][e2] + psum[2][e2] + psum[3][e2];
            pk0s[r2] = pk0[e2];
            pk1s[r2] = pk1[e2];
        }
    }
    __syncthreads();

    // ---- Phase D: wave-aligned composite, 2 sequential broadcast b128/elem ----
    {
        const int seg = wid;
        const bool act = (lane < NPX);
        const int pid = act ? lane : 0;
        const int px = tx*TILE + (pid % TILE);
        const int py = ty*TILE + (pid / TILE);
        const float pu = ((float)px + 0.5f - 48.0f) * FXI;
        const float pv = ((float)py + 0.5f - 48.0f) * FXI;

        const int per = (cnt + NSEG - 1) / NSEG;
        const int sA = min(seg * per, cnt);
        const int sB = min(sA + per, cnt);

        float T = 1.0f, cr = 0.0f, cg = 0.0f, cb = 0.0f;
        for (int s = sA; s < sB; s++) {
            float4 a0 = pk0s[s];                 // broadcast, affine addr
            float4 a1 = pk1s[s];                 // broadcast, affine addr
            unsigned int c01p = __float_as_uint(a1.z);
            float c0 = __half2float(__ushort_as_half((unsigned short)(c01p & 0xffffu)));
            float c1 = __half2float(__ushort_as_half((unsigned short)(c01p >> 16)));
            float c2 = __half2float(__ushort_as_half((unsigned short)(__float_as_uint(a1.w) & 0xffffu)));
            float dx = pu - a0.x;
            float dy = pv - a0.y;
            float pw = dx*(a0.z*dx + a0.w*dy) + a1.x*dy*dy;   // log2-scaled
            float al = fminf(a1.y * __builtin_amdgcn_exp2f(pw), 0.99f);
            float w = T * al;
            cr += w * c0;
            cg += w * c1;
            cb += w * c2;
            T *= (1.0f - al);
        }
        if (act) pix[seg*NPX + pid] = make_float4(cr, cg, cb, T);
    }
    __syncthreads();

    // ---- Phase E: merge 16 depth segments front-to-back, store ----
    if (t < NPX) {
        float orr = 0.0f, og = 0.0f, ob = 0.0f, T2 = 1.0f;
        #pragma unroll
        for (int s = 0; s < NSEG; s++) {
            float4 P = pix[s*NPX + t];
            orr += T2 * P.x;
            og  += T2 * P.y;
            ob  += T2 * P.z;
            T2  *= P.w;
        }
        int px = tx*TILE + (t % TILE);
        int py = ty*TILE + (t / TILE);
        int pixel = py * IMW + px;
        out[pixel*3+0] = orr;
        out[pixel*3+1] = og;
        out[pixel*3+2] = ob;
    }
}

extern "C" void kernel_launch(void* const* d_in, const int* in_sizes, int n_in,
                              void* d_out, int out_size, void* d_ws, size_t ws_size,
                              hipStream_t stream) {
    const float* pos   = (const float*)d_in[0];
    const float* rgb   = (const float*)d_in[1];
    const float* opa   = (const float*)d_in[2];
    const float* quat  = (const float*)d_in[3];
    const float* scale = (const float*)d_in[4];
    const float* rot   = (const float*)d_in[5];
    const float* tran  = (const float*)d_in[6];
    float* out = (float*)d_out;

    splat_k<<<NTILE, NTHR, 0, stream>>>(pos, rgb, opa, quat, scale, rot, tran, out);
}

// Round 21
// 13.788 us; speedup vs baseline: 1.0028x; 1.0028x over previous
//
#include <hip/hip_runtime.h>
#include <hip/hip_fp16.h>
#include <math.h>

#define N_G   4096
#define IMW   96
#define TILE  6             // 6x6 px tiles
#define TILES_X 16
#define NTILE (TILES_X*TILES_X)   // 256 blocks == 256 CUs
#define NTHR  1024          // 16 waves per block
#define NW    (NTHR/64)
#define NST   (N_G/NTHR)    // 4 cull stages
#define NPX   (TILE*TILE)   // 36 pixels per tile
#define NSEG  16            // depth segments per pixel == NW
#define BCAP  1536          // max bound-phase survivors per tile
#define CAP   512           // max exact survivors per tile
#define FXI   (1.0f/96.0f)
#define NEARP 0.3f
#define EPSV  1e-8f
#define LOG2E 1.4426950408889634f
#define LN2   0.6931471805599453f
#define CULL_K 16.0f        // drop alpha < opa * 2^-16 within tile

typedef unsigned long long ull;
typedef __attribute__((ext_vector_type(2))) unsigned long long ull2;

// R19 structure (best measured: 13.54 us) + Phase D early termination.
// A: cheap conservative bound cull (prefetched coalesced loads) -> gi list
// B: exact params + ellipse-AABB cull -> PACKED params (f16 colors) at slot p
// C: rank sort by (rr_bits,gi); scatter permutes the PARAM PAYLOAD
// D: wave-aligned composite, 2 broadcast b128/elem, __all(T<eps) early break
// E: merge + store.
__global__ __launch_bounds__(NTHR, 1) void splat_k(
    const float* __restrict__ pos, const float* __restrict__ rgb,
    const float* __restrict__ opa, const float* __restrict__ quat,
    const float* __restrict__ scale, const float* __restrict__ rot,
    const float* __restrict__ tran, float* __restrict__ out)
{
    __shared__ unsigned int bl[BCAP];
    __shared__ __align__(16) ull skey[CAP+2];
    __shared__ float4 pk0[CAP], pk1[CAP];     // unsorted packed params
    __shared__ float4 pk0s[CAP], pk1s[CAP];   // depth-sorted packed params
    __shared__ float4 pix[NSEG*NPX];
    __shared__ int psum[4][CAP];
    __shared__ int bcnt_sh, cnt_sh;

    const int t = threadIdx.x;
    const int tile = blockIdx.x;
    const int tx = tile % TILES_X, ty = tile / TILES_X;
    const float u0 = ((float)(tx*TILE) + 0.5f - 48.0f) * FXI;
    const float u1 = u0 + (TILE-1) * FXI;
    const float v0 = ((float)(ty*TILE) + 0.5f - 48.0f) * FXI;
    const float v1 = v0 + (TILE-1) * FXI;
    const int wid = t >> 6, lane = t & 63;

    if (t == 0) { bcnt_sh = 0; cnt_sh = 0; }

    float R00=rot[0],R01=rot[1],R02=rot[2];
    float R10=rot[3],R11=rot[4],R12=rot[5];
    float R20=rot[6],R21=rot[7],R22=rot[8];
    float t0=tran[0], t1=tran[1], t2=tran[2];

    // ---- Phase A prefetch: issue all 4 stages' loads up front ----
    float pp0[NST], pp1[NST], pp2[NST], po[NST], ps0[NST], ps1[NST], ps2[NST];
    #pragma unroll
    for (int st = 0; st < NST; st++) {
        int gi = st*NTHR + t;
        pp0[st]=pos[gi*3+0]; pp1[st]=pos[gi*3+1]; pp2[st]=pos[gi*3+2];
        po[st]=opa[gi];
        ps0[st]=scale[gi*3+0]; ps1[st]=scale[gi*3+1]; ps2[st]=scale[gi*3+2];
    }
    __syncthreads();   // counters initialized

    // ---- Phase A: cheap conservative bound cull, barrier-free compact ----
    #pragma unroll
    for (int st = 0; st < NST; st++) {
        int gi = st*NTHR + t;
        float x = R00*pp0[st] + R01*pp1[st] + R02*pp2[st] + t0;
        float y = R10*pp0[st] + R11*pp1[st] + R12*pp2[st] + t1;
        float z = R20*pp0[st] + R21*pp1[st] + R22*pp2[st] + t2;
        float invz = 1.0f/z;
        float mu = x*invz, mv = y*invz;

        // ||J*W||_F^2 == ||J||_F^2 (W orthonormal): 2/z^2 + (x^2+y^2)/z^4
        float inz2 = invz*invz;
        float fn = 2.0f*inz2 + (x*x + y*y)*inz2*inz2;
        float smax = fmaxf(fmaxf(fabsf(ps0[st]), fabsf(ps1[st])), fabsf(ps2[st])) + 1e-4f;
        float lmax = fn*smax*smax + EPSV;      // >= lam_max(cov2d)
        float amp = CULL_K + 1.0f + fminf(0.0f, po[st]*LOG2E);
        float r2b = amp * lmax * (2.0f*LN2) * 1.02f;

        float cu = fminf(fmaxf(mu, u0), u1);
        float cv = fminf(fmaxf(mv, v0), v1);
        float ddx = mu - cu, ddy = mv - cv;
        bool flag = (z > NEARP) && (amp > 0.0f) && (ddx*ddx + ddy*ddy <= r2b);

        ull m = __ballot(flag);
        int nm = __popcll(m);
        int base = 0;
        if (lane == 0 && nm) base = atomicAdd(&bcnt_sh, nm);
        base = __shfl(base, 0);
        if (flag) {
            int p = base + __popcll(m & ((1ull << lane) - 1ull));
            if (p < BCAP) bl[p] = (unsigned int)gi;
        }
    }
    __syncthreads();
    int bcnt = bcnt_sh; if (bcnt > BCAP) bcnt = BCAP;

    // ---- Phase B: exact params + ellipse-AABB cull, packed write ----
    for (int s0i = 0; s0i < bcnt; s0i += NTHR) {
        int s = s0i + t;
        bool flag = false;
        float4 o0, o1; float rr = 0.0f;
        unsigned int gi = 0;
        if (s < bcnt) {
            gi = bl[s];
            float p0=pos[gi*3+0], p1=pos[gi*3+1], p2=pos[gi*3+2];
            float x = R00*p0 + R01*p1 + R02*p2 + t0;
            float y = R10*p0 + R11*p1 + R12*p2 + t1;
            float z = R20*p0 + R21*p1 + R22*p2 + t2;
            rr = sqrtf(x*x + y*y + z*z);
            float invz = 1.0f/z;
            float mu = x*invz, mv = y*invz;

            float J02 = -x*invz*invz, J12 = -y*invz*invz;
            float JW00 = invz*R00 + J02*R20;
            float JW01 = invz*R01 + J02*R21;
            float JW02 = invz*R02 + J02*R22;
            float JW10 = invz*R10 + J12*R20;
            float JW11 = invz*R11 + J12*R21;
            float JW12 = invz*R12 + J12*R22;

            float qw=quat[gi*4+0], qx=quat[gi*4+1], qy=quat[gi*4+2], qz=quat[gi*4+3];
            float qn = sqrtf(qw*qw+qx*qx+qy*qy+qz*qz) + 1e-12f;
            float qi = 1.0f/qn;
            qw*=qi; qx*=qi; qy*=qi; qz*=qi;
            float Q00=1.f-2.f*(qy*qy+qz*qz), Q01=2.f*(qx*qy-qw*qz), Q02=2.f*(qx*qz+qw*qy);
            float Q10=2.f*(qx*qy+qw*qz), Q11=1.f-2.f*(qx*qx+qz*qz), Q12=2.f*(qy*qz-qw*qx);
            float Q20=2.f*(qx*qz-qw*qy), Q21=2.f*(qy*qz+qw*qx), Q22=1.f-2.f*(qx*qx+qy*qy);

            float sa=fabsf(scale[gi*3+0])+1e-4f;
            float sb=fabsf(scale[gi*3+1])+1e-4f;
            float sc=fabsf(scale[gi*3+2])+1e-4f;
            float A00=Q00*sa,A01=Q01*sb,A02=Q02*sc;
            float A10=Q10*sa,A11=Q11*sb,A12=Q12*sc;
            float A20=Q20*sa,A21=Q21*sb,A22=Q22*sc;
            float C00=A00*A00+A01*A01+A02*A02;
            float C01=A00*A10+A01*A11+A02*A12;
            float C02=A00*A20+A01*A21+A02*A22;
            float C11=A10*A10+A11*A11+A12*A12;
            float C12=A10*A20+A11*A21+A12*A22;
            float C22=A20*A20+A21*A21+A22*A22;
            float M00=JW00*C00+JW01*C01+JW02*C02;
            float M01=JW00*C01+JW01*C11+JW02*C12;
            float M02=JW00*C02+JW01*C12+JW02*C22;
            float M10=JW10*C00+JW11*C01+JW12*C02;
            float M11=JW10*C01+JW11*C11+JW12*C12;
            float M12=JW10*C02+JW11*C12+JW12*C22;
            float a  = M00*JW00+M01*JW01+M02*JW02 + EPSV;
            float d  = M10*JW10+M11*JW11+M12*JW12 + EPSV;
            float bb = 0.5f*((M00*JW10+M01*JW11+M02*JW12)+(M10*JW00+M11*JW01+M12*JW02));
            float invdet = 1.0f/(a*d - bb*bb);
            float iaP = -0.5f*d*invdet*LOG2E;
            float ibP =  bb*invdet*LOG2E;
            float idP = -0.5f*a*invdet*LOG2E;

            float sig_o = 1.0f/(1.0f+__expf(-opa[gi]));
            float opa_eff = (z > NEARP) ? sig_o : 0.0f;

            // exact ellipse-AABB cull: extent_u^2 = K*q11/detQ etc.
            float q00 = -iaP, q01 = -0.5f*ibP, q11 = -idP;
            float detQ = q00*q11 - q01*q01;
            float K = CULL_K + log2f(opa_eff);   // -inf when opa_eff==0

            float cu = fminf(fmaxf(mu, u0), u1);
            float cv = fminf(fmaxf(mv, v0), v1);
            float ddx = mu - cu, ddy = mv - cv;
            flag = (ddx*ddx*detQ <= K*q11) && (ddy*ddy*detQ <= K*q00);

            if (flag) {
                float c0 = 1.0f/(1.0f+__expf(-rgb[gi*3+0]));
                float c1 = 1.0f/(1.0f+__expf(-rgb[gi*3+1]));
                float c2 = 1.0f/(1.0f+__expf(-rgb[gi*3+2]));
                unsigned int c01p =
                    (unsigned int)__half_as_ushort(__float2half_rn(c0)) |
                    ((unsigned int)__half_as_ushort(__float2half_rn(c1)) << 16);
                unsigned int c2p =
                    (unsigned int)__half_as_ushort(__float2half_rn(c2));
                o0 = make_float4(mu, mv, iaP, ibP);
                o1 = make_float4(idP, opa_eff,
                                 __uint_as_float(c01p), __uint_as_float(c2p));
            }
        }
        ull m = __ballot(flag);
        int nm = __popcll(m);
        int base = 0;
        if (lane == 0 && nm) base = atomicAdd(&cnt_sh, nm);
        base = __shfl(base, 0);
        if (flag) {
            int p = base + __popcll(m & ((1ull << lane) - 1ull));
            if (p < CAP) {
                pk0[p] = o0; pk1[p] = o1;
                // key = (rr_bits, gi): globally unique -> reference's stable
                // argsort order restricted to survivors
                skey[p] = ((ull)__float_as_uint(rr) << 32) | gi;
            }
        }
    }
    __syncthreads();
    int cnt = cnt_sh; if (cnt > CAP) cnt = CAP;

    // ---- Phase C: rank sort; scatter permutes PARAM PAYLOAD into order ----
    if (t == 0 && (cnt & 1)) skey[cnt] = ~0ull;  // pad sorts last, never scattered
    __syncthreads();
    int cnt2 = cnt + (cnt & 1);
    int nq = cnt2 >> 1;                          // total ull2 words
    const ull2* sk2 = (const ull2*)skey;
    const int g = t >> 8, e = t & 255;
    const bool h1 = (e < cnt), h2 = (e + 256 < cnt);
    if (h1) {
        ull kv1 = skey[e];
        ull kv2 = h2 ? skey[e + 256] : 0;
        int wA = (nq * g) >> 2;
        int wB = (nq * (g+1)) >> 2;
        int c1 = 0, c2 = 0;
        for (int w = wA; w < wB; w++) {
            ull2 p = sk2[w];                     // broadcast: shared by both elems
            c1 += (p.x < kv1) ? 1 : 0;
            c1 += (p.y < kv1) ? 1 : 0;
            c2 += (p.x < kv2) ? 1 : 0;
            c2 += (p.y < kv2) ? 1 : 0;
        }
        psum[g][e] = c1;
        if (h2) psum[g][e + 256] = c2;
    }
    __syncthreads();
    if (t < 256 && h1) {
        int r1 = psum[0][e] + psum[1][e] + psum[2][e] + psum[3][e];
        pk0s[r1] = pk0[e];
        pk1s[r1] = pk1[e];
        if (h2) {
            int e2 = e + 256;
            int r2 = psum[0][e2] + psum[1][e2] + psum[2][e2] + psum[3][e2];
            pk0s[r2] = pk0[e2];
            pk1s[r2] = pk1[e2];
        }
    }
    __syncthreads();

    // ---- Phase D: wave-aligned composite + early termination ----
    {
        const int seg = wid;
        const bool act = (lane < NPX);
        const int pid = act ? lane : 0;
        const int px = tx*TILE + (pid % TILE);
        const int py = ty*TILE + (pid / TILE);
        const float pu = ((float)px + 0.5f - 48.0f) * FXI;
        const float pv = ((float)py + 0.5f - 48.0f) * FXI;

        const int per = (cnt + NSEG - 1) / NSEG;
        const int sA = min(seg * per, cnt);
        const int sB = min(sA + per, cnt);

        float T = 1.0f, cr = 0.0f, cg = 0.0f, cb = 0.0f;
        int s = sA;
        for (; s < sB; ) {
            int sE = min(s + 4, sB);
            #pragma unroll 4
            for (; s < sE; s++) {
                float4 a0 = pk0s[s];             // broadcast, affine addr
                float4 a1 = pk1s[s];             // broadcast, affine addr
                unsigned int c01p = __float_as_uint(a1.z);
                float c0 = __half2float(__ushort_as_half((unsigned short)(c01p & 0xffffu)));
                float c1 = __half2float(__ushort_as_half((unsigned short)(c01p >> 16)));
                float c2 = __half2float(__ushort_as_half((unsigned short)(__float_as_uint(a1.w) & 0xffffu)));
                float dx = pu - a0.x;
                float dy = pv - a0.y;
                float pw = dx*(a0.z*dx + a0.w*dy) + a1.x*dy*dy;   // log2-scaled
                float al = fminf(a1.y * __builtin_amdgcn_exp2f(pw), 0.99f);
                float w = T * al;
                cr += w * c0;
                cg += w * c1;
                cb += w * c2;
                T *= (1.0f - al);
            }
            // dropped tail contributes <= T * sum(w*c) <= 1e-7 * ~CAP << tol
            if (__all(T < 1e-7f)) break;
        }
        if (act) pix[seg*NPX + pid] = make_float4(cr, cg, cb, T);
    }
    __syncthreads();

    // ---- Phase E: merge 16 depth segments front-to-back, store ----
    if (t < NPX) {
        float orr = 0.0f, og = 0.0f, ob = 0.0f, T2 = 1.0f;
        #pragma unroll
        for (int s = 0; s < NSEG; s++) {
            float4 P = pix[s*NPX + t];
            orr += T2 * P.x;
            og  += T2 * P.y;
            ob  += T2 * P.z;
            T2  *= P.w;
        }
        int px = tx*TILE + (t % TILE);
        int py = ty*TILE + (t / TILE);
        int pixel = py * IMW + px;
        out[pixel*3+0] = orr;
        out[pixel*3+1] = og;
        out[pixel*3+2] = ob;
    }
}

extern "C" void kernel_launch(void* const* d_in, const int* in_sizes, int n_in,
                              void* d_out, int out_size, void* d_ws, size_t ws_size,
                              hipStream_t stream) {
    const float* pos   = (const float*)d_in[0];
    const float* rgb   = (const float*)d_in[1];
    const float* opa   = (const float*)d_in[2];
    const float* quat  = (const float*)d_in[3];
    const float* scale = (const float*)d_in[4];
    const float* rot   = (const float*)d_in[5];
    const float* tran  = (const float*)d_in[6];
    float* out = (float*)d_out;

    splat_k<<<NTILE, NTHR, 0, stream>>>(pos, rgb, opa, quat, scale, rot, tran, out);
}